// Round 8
// baseline (3345.723 us; speedup 1.0000x reference)
//
#include <hip/hip_runtime.h>
#include <hip/hip_cooperative_groups.h>

namespace cg = cooperative_groups;

#define Q 16

__device__ __forceinline__ float wsum(float v){
  #pragma unroll
  for(int o=32;o;o>>=1) v += __shfl_xor(v,o);
  return v;
}
__device__ __forceinline__ float wmaxr(float v){
  #pragma unroll
  for(int o=32;o;o>>=1) v = fmaxf(v,__shfl_xor(v,o));
  return v;
}

// One persistent cooperative kernel: init + 10 BP iterations + finalize.
// Phases separated by grid.sync(); all control flow is grid-uniform.
__global__ void __launch_bounds__(256, 4) k_bp(
    const int* __restrict__ src, const int* __restrict__ dst,
    const float* __restrict__ psi0, const float* __restrict__ msg0,
    const float* __restrict__ betap,
    float* __restrict__ msgA, float* __restrict__ nl,
    int* __restrict__ eid, int* __restrict__ offs, int* __restrict__ cursor,
    int* __restrict__ bsum, int* __restrict__ deg,
    float* __restrict__ hpart, float* __restrict__ diffpart,
    float* __restrict__ edgepart, float* __restrict__ colpart,
    float* __restrict__ degpart, float* __restrict__ entpart,
    float* __restrict__ red2, float* __restrict__ out,
    int M, int N, int E, int NQ, float mean_w, float m2)
{
  cg::grid_group grid = cg::this_grid();
  const int nb   = gridDim.x;
  const int bid  = blockIdx.x;
  const int t    = threadIdx.x;
  const int tid  = bid*256 + t;
  const int nth  = nb*256;
  const int lane = t & 63;
  const int wid  = t >> 6;
  const int sub  = lane >> 4;
  const int q16  = lane & 15;
  const int gwave  = tid >> 6;
  const int nwaves = nth >> 6;
  const float beta = *betap;
  const float eb   = __expf(beta) - 1.0f;

  __shared__ float smf[16][17];
  __shared__ float hq_sm[16];
  __shared__ float smx[4];
  __shared__ int   smi[256];
  __shared__ int   brk_sm;

  // ================= P0: deg histogram + h0 partials from psi0 =============
  for (int e = tid; e < E; e += nth) atomicAdd(&deg[dst[e]], 1);
  {
    float pv[Q];
    #pragma unroll
    for (int q=0;q<Q;q++) pv[q]=0.0f;
    for (int n = tid; n < N; n += nth){
      const float4* a = (const float4*)(psi0 + (size_t)n*Q);
      #pragma unroll
      for (int i=0;i<4;i++){ float4 x=a[i]; pv[4*i]+=x.x; pv[4*i+1]+=x.y; pv[4*i+2]+=x.z; pv[4*i+3]+=x.w; }
    }
    #pragma unroll
    for (int q=0;q<Q;q++){
      float s = wsum(pv[q]);
      if (lane==0) smf[wid][q] = s;
    }
    __syncthreads();
    if (t < Q)
      hpart[(size_t)bid*Q + t] = smf[0][t]+smf[1][t]+smf[2][t]+smf[3][t];
  }
  grid.sync();

  // ================= P1: block-local scan of deg ============================
  const int nbs = (N + 255)/256;
  if (bid < nbs){
    const int i = bid*256 + t;
    const int v = (i<N) ? deg[i] : 0;
    smi[t] = v; __syncthreads();
    #pragma unroll
    for (int o=1;o<256;o<<=1){
      int x = (t>=o) ? smi[t-o] : 0;
      __syncthreads();
      smi[t] += x;
      __syncthreads();
    }
    if (i<N) offs[i] = smi[t] - v;
    if (t==255) bsum[bid] = smi[t];
  }
  grid.sync();

  // ================= P2: scan block sums (single block) =====================
  if (bid == 0){
    const int v = (t<nbs) ? bsum[t] : 0;
    smi[t] = v; __syncthreads();
    #pragma unroll
    for (int o=1;o<256;o<<=1){
      int x = (t>=o) ? smi[t-o] : 0;
      __syncthreads();
      smi[t] += x;
      __syncthreads();
    }
    if (t<nbs) bsum[t] = smi[t] - v;
  }
  grid.sync();

  // ================= P3: add back + init cursor =============================
  for (int i = tid; i < N; i += nth){
    const int o = offs[i] + bsum[i>>8];
    offs[i] = o; cursor[i] = o;
  }
  if (tid == 0) offs[N] = E;
  grid.sync();

  // ================= P4: CSR fill ===========================================
  for (int e = tid; e < E; e += nth){
    const int p = atomicAdd(&cursor[dst[e]], 1);
    eid[p] = e;
  }
  grid.sync();

  // ================= P5: initial node_log from msg0 =========================
  for (int n = gwave; n < N; n += nwaves){
    const int start = offs[n], end = offs[n+1];
    float acc = 0.0f;
    int i = start + sub;
    for (; i + 4 < end; i += 8){
      const int e0 = eid[i], e1 = eid[i+4];
      const float x0 = msg0[(size_t)e0*Q + q16];
      const float x1 = msg0[(size_t)e1*Q + q16];
      acc += __logf(fmaf(x0, eb, 1.0f)) + __logf(fmaf(x1, eb, 1.0f));
    }
    if (i < end) acc += __logf(fmaf(msg0[(size_t)eid[i]*Q + q16], eb, 1.0f));
    acc += __shfl_xor(acc, 16);
    acc += __shfl_xor(acc, 32);
    if (sub == 0) nl[(size_t)n*Q + q16] = acc;
  }
  grid.sync();

  // ================= BP iterations ==========================================
  float hq[Q];
  for (int k = 0; k < 10; ++k){
    // ---- edge prologue: fold h from hpart; fold diff; uniform break ----
    {
      const int r0 = t>>4, qq = t&15;
      float s = 0.0f;
      for (int r = r0; r < nb; r += 16) s += hpart[(size_t)r*Q + qq];
      smf[r0][qq] = s;
      __syncthreads();
      if (t < Q){
        float tot = 0.0f;
        #pragma unroll
        for (int i=0;i<16;i++) tot += smf[i][t];
        hq_sm[t] = -beta * mean_w * tot;
      }
      float dm = 0.0f;
      for (int i = t; i < nb; i += 256) dm = fmaxf(dm, diffpart[i]);
      dm = wmaxr(dm);
      if (lane == 0) smx[wid] = dm;
      __syncthreads();
      if (t == 0)
        brk_sm = (k > 0 &&
          fmaxf(fmaxf(smx[0],smx[1]), fmaxf(smx[2],smx[3])) < 0.01f);
      __syncthreads();
      if (brk_sm) break;                        // grid-uniform (same global data)
      #pragma unroll
      for (int i=0;i<Q;i++) hq[i] = hq_sm[i];
    }
    // ---- edge phase: grid-stride pairs, in-place msg update ----
    const float* mc = (k==0) ? msg0 : msgA;
    float dloc = 0.0f;
    for (int p = tid; p < M; p += nth){
      const int u = src[p], v = dst[p];
      const float4* a  = (const float4*)(mc + (size_t)p*Q);
      const float4* b  = (const float4*)(mc + ((size_t)p + (size_t)M)*Q);
      const float4* u4 = (const float4*)(nl + (size_t)u*Q);
      const float4* v4 = (const float4*)(nl + (size_t)v*Q);
      float4 a0=a[0], a1=a[1], a2=a[2], a3=a[3];
      float4 b0=b[0], b1=b[1], b2=b[2], b3=b[3];
      float4 un0=u4[0], un1=u4[1], un2=u4[2], un3=u4[3];
      float4 vn0=v4[0], vn1=v4[1], vn2=v4[2], vn3=v4[3];
      float muv[Q], mvu[Q], nlu[Q], nlv[Q];
      #define UNP(arr,r0,r1,r2,r3) \
        arr[0]=r0.x;arr[1]=r0.y;arr[2]=r0.z;arr[3]=r0.w; \
        arr[4]=r1.x;arr[5]=r1.y;arr[6]=r1.z;arr[7]=r1.w; \
        arr[8]=r2.x;arr[9]=r2.y;arr[10]=r2.z;arr[11]=r2.w; \
        arr[12]=r3.x;arr[13]=r3.y;arr[14]=r3.z;arr[15]=r3.w;
      UNP(muv,a0,a1,a2,a3) UNP(mvu,b0,b1,b2,b3)
      UNP(nlu,un0,un1,un2,un3) UNP(nlv,vn0,vn1,vn2,vn3)
      #undef UNP
      float tuv[Q], tvu[Q];
      #pragma unroll
      for (int q=0;q<Q;q++){
        float lsuv = __logf(fmaf(muv[q], eb, 1.0f));
        float lsvu = __logf(fmaf(mvu[q], eb, 1.0f));
        tuv[q] = nlu[q] - lsvu + hq[q];
        tvu[q] = nlv[q] - lsuv + hq[q];
      }
      float m1 = tuv[0], m2l = tvu[0];
      #pragma unroll
      for (int q=1;q<Q;q++){ m1=fmaxf(m1,tuv[q]); m2l=fmaxf(m2l,tvu[q]); }
      float s1=0.0f, s2=0.0f;
      #pragma unroll
      for (int q=0;q<Q;q++){
        tuv[q]=__expf(tuv[q]-m1);  s1+=tuv[q];
        tvu[q]=__expf(tvu[q]-m2l); s2+=tvu[q];
      }
      const float r1 = 1.0f/s1, r2 = 1.0f/s2;
      float d1=0.0f, d2=0.0f;
      #pragma unroll
      for (int q=0;q<Q;q++){
        float nuv = tuv[q]*r1, nvu = tvu[q]*r2;
        d1 += fabsf(nuv - muv[q]);
        d2 += fabsf(nvu - mvu[q]);
        muv[q]=nuv; mvu[q]=nvu;
      }
      dloc = fmaxf(dloc, fmaxf(d1,d2));
      float4* o1 = (float4*)(msgA + (size_t)p*Q);
      float4* o2 = (float4*)(msgA + ((size_t)p + (size_t)M)*Q);
      #pragma unroll
      for (int i=0;i<4;i++){
        o1[i] = make_float4(muv[4*i],muv[4*i+1],muv[4*i+2],muv[4*i+3]);
        o2[i] = make_float4(mvu[4*i],mvu[4*i+1],mvu[4*i+2],mvu[4*i+3]);
      }
    }
    {
      float wm = wmaxr(dloc);
      if (lane == 0) smx[wid] = wm;
      __syncthreads();
      if (t == 0)
        diffpart[bid] = fmaxf(fmaxf(smx[0],smx[1]), fmaxf(smx[2],smx[3]));
    }
    grid.sync();

    // ---- gather phase: nl + psi + per-block h partials ----
    float hacc = 0.0f;
    for (int n = gwave; n < N; n += nwaves){
      const int start = offs[n], end = offs[n+1];
      float acc = 0.0f;
      int i = start + sub;
      for (; i + 4 < end; i += 8){
        const int e0 = eid[i], e1 = eid[i+4];
        const float x0 = msgA[(size_t)e0*Q + q16];
        const float x1 = msgA[(size_t)e1*Q + q16];
        acc += __logf(fmaf(x0, eb, 1.0f)) + __logf(fmaf(x1, eb, 1.0f));
      }
      if (i < end) acc += __logf(fmaf(msgA[(size_t)eid[i]*Q + q16], eb, 1.0f));
      acc += __shfl_xor(acc, 16);
      acc += __shfl_xor(acc, 32);
      if (sub == 0) nl[(size_t)n*Q + q16] = acc;
      float tv = acc + hq[q16];
      float m = tv;
      #pragma unroll
      for (int o=1;o<16;o<<=1) m = fmaxf(m, __shfl_xor(m,o));
      float ex = __expf(tv-m);
      float s = ex;
      #pragma unroll
      for (int o=1;o<16;o<<=1) s += __shfl_xor(s,o);
      const float pq = ex/s;
      if (sub == 0){
        out[(size_t)n*Q + q16] = pq;     // psi lives in d_out
        hacc += pq;
      }
    }
    __syncthreads();
    if (sub == 0) smf[wid][q16] = hacc;
    __syncthreads();
    if (t < Q)
      hpart[(size_t)bid*Q + t] = smf[0][t]+smf[1][t]+smf[2][t]+smf[3][t];
    grid.sync();
  }

  // ================= F0: edge-term partials + node-stat partials ============
  {
    float ed = 0.0f;
    for (int p = tid; p < M; p += nth){
      const int u = src[p], v = dst[p];
      const float4* a = (const float4*)(out + (size_t)u*Q);
      const float4* b = (const float4*)(out + (size_t)v*Q);
      float d = 0.0f;
      #pragma unroll
      for (int i=0;i<4;i++){
        float4 x=a[i], y=b[i];
        d += x.x*y.x + x.y*y.y + x.z*y.z + x.w*y.w;
      }
      ed += 2.0f*d;
    }
    ed = wsum(ed);
    if (lane == 0) smx[wid] = ed;
    __syncthreads();
    if (t == 0) edgepart[bid] = smx[0]+smx[1]+smx[2]+smx[3];

    float ca[Q], da[Q]; float ea = 0.0f;
    #pragma unroll
    for (int q=0;q<Q;q++){ ca[q]=0.0f; da[q]=0.0f; }
    for (int n = tid; n < N; n += nth){
      const float4* a = (const float4*)(out + (size_t)n*Q);
      float pv[Q];
      #pragma unroll
      for (int i=0;i<4;i++){ float4 x=a[i]; pv[4*i]=x.x; pv[4*i+1]=x.y; pv[4*i+2]=x.z; pv[4*i+3]=x.w; }
      const float dg = (float)deg[n];
      #pragma unroll
      for (int q=0;q<Q;q++){
        ca[q] += pv[q];
        da[q] += pv[q]*dg;
        ea    -= pv[q]*__logf(pv[q]+1e-12f);
      }
    }
    __syncthreads();
    #pragma unroll
    for (int q=0;q<Q;q++){
      float s = wsum(ca[q]);
      if (lane == 0) smf[wid][q] = s;
    }
    __syncthreads();
    if (t < Q) colpart[(size_t)bid*Q + t] = smf[0][t]+smf[1][t]+smf[2][t]+smf[3][t];
    __syncthreads();
    #pragma unroll
    for (int q=0;q<Q;q++){
      float s = wsum(da[q]);
      if (lane == 0) smf[wid][q] = s;
    }
    __syncthreads();
    if (t < Q) degpart[(size_t)bid*Q + t] = smf[0][t]+smf[1][t]+smf[2][t]+smf[3][t];
    float se = wsum(ea);
    __syncthreads();
    if (lane == 0) smx[wid] = se;
    __syncthreads();
    if (t == 0) entpart[bid] = smx[0]+smx[1]+smx[2]+smx[3];
  }
  grid.sync();

  // ================= F1: slice reductions ===================================
  if (bid < 16){
    const int chunk = (nb+15)/16;
    const int rbeg = bid*chunk;
    const int rend = min(rbeg+chunk, nb);
    const int qq = t&15, r0 = t>>4;
    float cs=0.0f, ds=0.0f;
    for (int r = rbeg+r0; r < rend; r += 16){
      cs += colpart[(size_t)r*Q + qq];
      ds += degpart[(size_t)r*Q + qq];
    }
    smf[r0][qq] = cs; __syncthreads();
    if (t < Q){
      float tot=0.0f;
      #pragma unroll
      for (int i=0;i<16;i++) tot += smf[i][t];
      red2[bid*Q + t] = tot;
    }
    __syncthreads();
    smf[r0][qq] = ds; __syncthreads();
    if (t < Q){
      float tot=0.0f;
      #pragma unroll
      for (int i=0;i<16;i++) tot += smf[i][t];
      red2[256 + bid*Q + t] = tot;
    }
  } else if (bid == 16){
    float s = 0.0f;
    for (int i = t; i < nb; i += 256) s += entpart[i];
    s = wsum(s);
    if (lane == 0) smx[wid] = s;
    __syncthreads();
    if (t == 0) red2[512] = smx[0]+smx[1]+smx[2]+smx[3];
  } else if (bid == 17){
    float s = 0.0f;
    for (int i = t; i < nb; i += 256) s += edgepart[i];
    s = wsum(s);
    if (lane == 0) smx[wid] = s;
    __syncthreads();
    if (t == 0) red2[513] = smx[0]+smx[1]+smx[2]+smx[3];
  }
  grid.sync();

  // ================= F2: final scalars ======================================
  if (bid == 0){
    const int qq = t&15, r0 = t>>4;
    smf[r0][qq] = red2[r0*Q + qq];        // col slices
    __syncthreads();
    float colq = 0.0f;
    if (t < Q){
      #pragma unroll
      for (int i=0;i<16;i++) colq += smf[i][t];
    }
    __syncthreads();
    smf[r0][qq] = red2[256 + r0*Q + qq];  // deg slices
    __syncthreads();
    float degq = 0.0f;
    if (t < Q){
      #pragma unroll
      for (int i=0;i<16;i++) degq += smf[i][t];
    }
    __syncthreads();
    if (t < Q){ smf[0][t] = colq; smf[1][t] = degq; }
    __syncthreads();
    if (t == 0){
      float reg = 0.0f, dt = 0.0f;
      for (int i=0;i<Q;i++){
        float d = smf[0][i]/(float)N - 1.0f/(float)Q; reg += d*d;
        float s = smf[1][i]/m2; dt += s*s;
      }
      out[NQ+0] = reg * 4.0f;                                // * sqrt(16)
      out[NQ+1] = red2[512]/(float)N / 2.7725887222397811f;  // / log(16)
      out[NQ+2] = red2[513]/m2 - dt;
    }
  }
}

extern "C" void kernel_launch(void* const* d_in, const int* in_sizes, int n_in,
                              void* d_out, int out_size, void* d_ws, size_t ws_size,
                              hipStream_t stream)
{
  const int*   src   = (const int*)  d_in[0];
  const int*   dst   = (const int*)  d_in[1];
  // d_in[2] = rev : structurally rev[p]=p+M / p-M, exploited directly
  const float* psi0  = (const float*)d_in[3];
  const float* msg0  = (const float*)d_in[4];
  const float* betap = (const float*)d_in[5];

  const int E  = in_sizes[0];
  const int M  = E/2;
  const int NQ = in_sizes[3];
  const int N  = NQ/Q;
  const float mean_w = (float)((double)E/((double)N*(double)N));
  const float m2 = (float)E;

  // grid sizing: co-resident blocks only (cooperative requirement)
  int dev = 0; hipGetDevice(&dev);
  int nCU = 256;
  hipDeviceGetAttribute(&nCU, hipDeviceAttributeMultiprocessorCount, dev);
  int bpc = 1;
  hipOccupancyMaxActiveBlocksPerMultiprocessor(&bpc, k_bp, 256, 0);
  if (bpc < 1) bpc = 1;
  int nb = nCU * bpc;
  if (nb > 1024) nb = 1024;   // cap: keeps per-iteration h-fold cheap
  if (nb < 256)  nb = 256;    // floor: scan phase needs >= ceil(N/256) blocks

  const int NBMAX = 2048;
  char* w = (char*)d_ws;
  float* msgA    = (float*)w; w += (size_t)E*Q*sizeof(float);
  float* nl      = (float*)w; w += (size_t)NQ*sizeof(float);
  int*   eid     = (int*)  w; w += (size_t)E*sizeof(int);
  int*   offs    = (int*)  w; w += (size_t)(N+16)*sizeof(int);
  int*   cursor  = (int*)  w; w += (size_t)(N+16)*sizeof(int);
  int*   bsum    = (int*)  w; w += 256*sizeof(int);
  float* hpart   = (float*)w; w += (size_t)NBMAX*Q*sizeof(float);
  float* diffpart= (float*)w; w += (size_t)NBMAX*sizeof(float);
  float* edgepart= (float*)w; w += (size_t)NBMAX*sizeof(float);
  float* colpart = (float*)w; w += (size_t)NBMAX*Q*sizeof(float);
  float* degpart = (float*)w; w += (size_t)NBMAX*Q*sizeof(float);
  float* entpart = (float*)w; w += (size_t)NBMAX*sizeof(float);
  float* red2    = (float*)w; w += 1024*sizeof(float);
  int*   deg     = (int*)  w; w += (size_t)(N+16)*sizeof(int);

  float* out = (float*)d_out;   // psi [N,Q]; scalars at NQ..NQ+2

  hipMemsetAsync(deg, 0, (size_t)(N+16)*sizeof(int), stream);

  int Mi=M, Ni=N, Ei=E, NQi=NQ; float mwi=mean_w, m2i=m2;
  void* args[] = {
    (void*)&src, (void*)&dst, (void*)&psi0, (void*)&msg0, (void*)&betap,
    (void*)&msgA, (void*)&nl, (void*)&eid, (void*)&offs, (void*)&cursor,
    (void*)&bsum, (void*)&deg, (void*)&hpart, (void*)&diffpart,
    (void*)&edgepart, (void*)&colpart, (void*)&degpart, (void*)&entpart,
    (void*)&red2, (void*)&out,
    (void*)&Mi, (void*)&Ni, (void*)&Ei, (void*)&NQi, (void*)&mwi, (void*)&m2i
  };
  hipLaunchCooperativeKernel((void*)k_bp, dim3(nb), dim3(256), args, 0, stream);
}

// Round 9
// 1980.055 us; speedup vs baseline: 1.6897x; 1.6897x over previous
//
#include <hip/hip_runtime.h>

#define Q 16
#define SCAN_B 256

__device__ __forceinline__ float wsum(float v){
  #pragma unroll
  for(int o=32;o;o>>=1) v += __shfl_xor(v,o);
  return v;
}
__device__ __forceinline__ float wmaxr(float v){
  #pragma unroll
  for(int o=32;o;o>>=1) v = fmaxf(v,__shfl_xor(v,o));
  return v;
}

// ---- edge kernel: 16 lanes per undirected pair, one q per lane ----
// Register footprint ~10 floats/lane (vs 100+ in the thread-per-pair form,
// which either spilled (R8 coop, VGPR=64) or serialized loads (R6, VGPR=44)).
__global__ void __launch_bounds__(256, 4) k_edge16(
    const int* __restrict__ src, const int* __restrict__ dst,
    const float* msg_in, float* msg_out,
    const float* __restrict__ nl, const float* __restrict__ hc,
    const float* __restrict__ betap,
    float* __restrict__ diffpart, const int* __restrict__ donep, int M)
{
  if (*donep) return;
  const float eb = __expf(*betap) - 1.0f;
  const int q = threadIdx.x & 15;
  const float hq = hc[q];
  const int grp  = (blockIdx.x*blockDim.x + threadIdx.x) >> 4;
  const int ngrp = (gridDim.x*blockDim.x) >> 4;
  float dloc = 0.0f;
  for (int p = grp; p < M; p += ngrp){
    const int u = src[p], v = dst[p];
    const float muv = msg_in[(size_t)p*Q + q];
    const float mvu = msg_in[((size_t)p + (size_t)M)*Q + q];
    const float nlu = nl[(size_t)u*Q + q];
    const float nlv = nl[(size_t)v*Q + q];
    const float lsuv = __logf(fmaf(muv, eb, 1.0f));   // logS of u->v
    const float lsvu = __logf(fmaf(mvu, eb, 1.0f));   // logS of v->u
    float tuv = nlu - lsvu + hq;                      // cavity removes reverse
    float tvu = nlv - lsuv + hq;
    float m1 = tuv, m2 = tvu;
    #pragma unroll
    for (int o=1;o<16;o<<=1){
      m1 = fmaxf(m1, __shfl_xor(m1,o));
      m2 = fmaxf(m2, __shfl_xor(m2,o));
    }
    const float e1 = __expf(tuv-m1), e2 = __expf(tvu-m2);
    float s1 = e1, s2 = e2;
    #pragma unroll
    for (int o=1;o<16;o<<=1){
      s1 += __shfl_xor(s1,o);
      s2 += __shfl_xor(s2,o);
    }
    const float nuv = e1/s1, nvu = e2/s2;
    float d1 = fabsf(nuv-muv), d2 = fabsf(nvu-mvu);
    #pragma unroll
    for (int o=1;o<16;o<<=1){
      d1 += __shfl_xor(d1,o);
      d2 += __shfl_xor(d2,o);
    }
    dloc = fmaxf(dloc, fmaxf(d1,d2));
    msg_out[(size_t)p*Q + q] = nuv;
    msg_out[((size_t)p + (size_t)M)*Q + q] = nvu;
  }
  __shared__ float smx[4];
  float wm = wmaxr(dloc);
  if ((threadIdx.x & 63) == 0) smx[threadIdx.x>>6] = wm;
  __syncthreads();
  if (threadIdx.x == 0)
    diffpart[blockIdx.x] = fmaxf(fmaxf(smx[0],smx[1]), fmaxf(smx[2],smx[3]));
}

// ---- gather: grid-stride (nbG fat blocks), wave per node; CSR gather.
// mode=1 additionally: psi, per-block h partials, and LAST BLOCK folds
// hpart (nbG*16 = 64KB -> ~4us, R5 lesson: single-block folds KB-scale only),
// folds diffpart, writes h, sets done. Loop = 2 dispatches/iter.
__global__ void __launch_bounds__(256, 4) k_gather2(
    const float* __restrict__ msg, const int* __restrict__ offs,
    const int* __restrict__ eid,
    float* __restrict__ nl, const float* __restrict__ hc,
    float* __restrict__ psi, const float* __restrict__ betap,
    int* __restrict__ donep, float* __restrict__ hpart,
    const float* __restrict__ diffpart, int ndiff,
    float* __restrict__ h, int* __restrict__ cnt,
    int nbG, float mean_w, int N, int mode)
{
  if (mode && *donep) return;
  const float beta = *betap;
  const float eb = __expf(beta) - 1.0f;
  const int lane = threadIdx.x & 63;
  const int wid  = threadIdx.x >> 6;
  const int sub  = lane >> 4, q16 = lane & 15;
  const int gw  = (blockIdx.x*blockDim.x + threadIdx.x) >> 6;
  const int nwv = (gridDim.x*blockDim.x) >> 6;
  const float hq = hc[q16];
  float hacc = 0.0f;
  for (int n = gw; n < N; n += nwv){
    const int start = offs[n], end = offs[n+1];
    float acc = 0.0f;
    int i = start + sub;
    for (; i + 4 < end; i += 8){
      const int e0 = eid[i], e1 = eid[i+4];
      acc += __logf(fmaf(msg[(size_t)e0*Q + q16], eb, 1.0f))
           + __logf(fmaf(msg[(size_t)e1*Q + q16], eb, 1.0f));
    }
    if (i < end) acc += __logf(fmaf(msg[(size_t)eid[i]*Q + q16], eb, 1.0f));
    acc += __shfl_xor(acc, 16);
    acc += __shfl_xor(acc, 32);
    if (sub == 0) nl[(size_t)n*Q + q16] = acc;
    if (mode){
      float tv = acc + hq;
      float m = tv;
      #pragma unroll
      for (int o=1;o<16;o<<=1) m = fmaxf(m, __shfl_xor(m,o));
      float ex = __expf(tv-m);
      float s = ex;
      #pragma unroll
      for (int o=1;o<16;o<<=1) s += __shfl_xor(s,o);
      const float pq = ex/s;
      if (sub == 0){
        psi[(size_t)n*Q + q16] = pq;
        hacc += pq;
      }
    }
  }
  if (!mode) return;
  __shared__ float smf[4][17];
  __shared__ float smx[4];
  __shared__ float smg[16][17];
  __shared__ int amLast;
  if (sub == 0) smf[wid][q16] = hacc;
  __syncthreads();
  if (threadIdx.x < Q)
    hpart[(size_t)blockIdx.x*Q + threadIdx.x] =
      smf[0][threadIdx.x]+smf[1][threadIdx.x]+smf[2][threadIdx.x]+smf[3][threadIdx.x];
  __threadfence();
  if (threadIdx.x == 0) amLast = (atomicAdd(cnt, 1) == nbG-1);
  __syncthreads();
  if (!amLast) return;
  // ---- last block: fold hpart -> h, fold diff -> done ----
  {
    const int g = threadIdx.x>>4, qq = threadIdx.x&15;
    float s = 0.0f;
    for (int r = g; r < nbG; r += 16) s += hpart[(size_t)r*Q + qq];
    smg[g][qq] = s; __syncthreads();
    if (threadIdx.x < Q){
      float tot = 0.0f;
      #pragma unroll
      for (int i=0;i<16;i++) tot += smg[i][threadIdx.x];
      h[threadIdx.x] = -beta * mean_w * tot;
    }
  }
  float dm = 0.0f;
  for (int i = threadIdx.x; i < ndiff; i += 256) dm = fmaxf(dm, diffpart[i]);
  dm = wmaxr(dm);
  if (lane == 0) smx[wid] = dm;
  __syncthreads();
  if (threadIdx.x == 0 &&
      fmaxf(fmaxf(smx[0],smx[1]), fmaxf(smx[2],smx[3])) < 0.01f) *donep = 1;
}

// ---- h partials over psi0 (init only) ----
__global__ void __launch_bounds__(256) k_h_part(
    const float* __restrict__ psi, float* __restrict__ hpart, int N)
{
  const int n = blockIdx.x*blockDim.x + threadIdx.x;
  float pv[Q];
  if (n < N) {
    const float4* a = (const float4*)(psi + (size_t)n*Q);
    #pragma unroll
    for (int i=0;i<4;i++){ float4 t=a[i]; pv[4*i]=t.x; pv[4*i+1]=t.y; pv[4*i+2]=t.z; pv[4*i+3]=t.w; }
  } else {
    #pragma unroll
    for (int q=0;q<Q;q++) pv[q]=0.0f;
  }
  __shared__ float sm[4][Q];
  const int wid = threadIdx.x>>6, lane = threadIdx.x&63;
  #pragma unroll
  for (int q=0;q<Q;q++){
    float s = wsum(pv[q]);
    if (lane == 0) sm[wid][q] = s;
  }
  __syncthreads();
  if (threadIdx.x < Q)
    hpart[(size_t)blockIdx.x*Q + threadIdx.x] =
      sm[0][threadIdx.x]+sm[1][threadIdx.x]+sm[2][threadIdx.x]+sm[3][threadIdx.x];
}

__global__ void __launch_bounds__(256) k_hfin(
    const float* __restrict__ hpart, float* __restrict__ h,
    const float* __restrict__ betap, int nb, float mean_w)
{
  const int t = threadIdx.x, g = t>>4, q = t&15;
  float s = 0.0f;
  for (int b = g; b < nb; b += 16) s += hpart[(size_t)b*Q + q];
  __shared__ float sm[16][17];
  sm[g][q] = s; __syncthreads();
  if (t < Q){
    float tot = 0.0f;
    #pragma unroll
    for (int i=0;i<16;i++) tot += sm[i][t];
    h[t] = -(*betap) * mean_w * tot;
  }
}

// ---- CSR build ----
__global__ void __launch_bounds__(256) k_deg(
    const int* __restrict__ dst, int* __restrict__ deg, int E)
{
  const int e = blockIdx.x*blockDim.x + threadIdx.x;
  if (e < E) atomicAdd(&deg[dst[e]], 1);
}

__global__ void __launch_bounds__(SCAN_B) k_scan1(
    const int* __restrict__ deg, int* __restrict__ offs,
    int* __restrict__ bsum, int N)
{
  __shared__ int sm[SCAN_B];
  const int i = blockIdx.x*SCAN_B + threadIdx.x;
  const int v = (i<N) ? deg[i] : 0;
  sm[threadIdx.x] = v; __syncthreads();
  #pragma unroll
  for (int o=1;o<SCAN_B;o<<=1){
    int t = (threadIdx.x>=o) ? sm[threadIdx.x-o] : 0;
    __syncthreads();
    sm[threadIdx.x] += t;
    __syncthreads();
  }
  if (i<N) offs[i] = sm[threadIdx.x] - v;           // block-local exclusive
  if (threadIdx.x==SCAN_B-1) bsum[blockIdx.x] = sm[threadIdx.x];
}

__global__ void __launch_bounds__(SCAN_B) k_scan2(int* __restrict__ bsum, int nb)
{
  __shared__ int sm[SCAN_B];
  const int v = (threadIdx.x<nb) ? bsum[threadIdx.x] : 0;
  sm[threadIdx.x] = v; __syncthreads();
  #pragma unroll
  for (int o=1;o<SCAN_B;o<<=1){
    int t = (threadIdx.x>=o) ? sm[threadIdx.x-o] : 0;
    __syncthreads();
    sm[threadIdx.x] += t;
    __syncthreads();
  }
  if (threadIdx.x<nb) bsum[threadIdx.x] = sm[threadIdx.x] - v;  // exclusive
}

__global__ void __launch_bounds__(SCAN_B) k_scan3(
    int* __restrict__ offs, int* __restrict__ cursor,
    const int* __restrict__ bsum, int N, int E)
{
  const int i = blockIdx.x*SCAN_B + threadIdx.x;
  if (i<N){
    const int o = offs[i] + bsum[blockIdx.x];
    offs[i] = o; cursor[i] = o;
  }
  if (i==0) offs[N] = E;
}

__global__ void __launch_bounds__(256) k_fill(
    const int* __restrict__ dst, int* __restrict__ cursor,
    int* __restrict__ eid, int E)
{
  const int e = blockIdx.x*blockDim.x + threadIdx.x;
  if (e < E){
    const int p = atomicAdd(&cursor[dst[e]], 1);
    eid[p] = e;
  }
}

// ---- finalization: per-block partials, no atomics ----
__global__ void __launch_bounds__(256) k_edge_term(
    const int* __restrict__ src, const int* __restrict__ dst,
    const float* __restrict__ psi, float* __restrict__ edgepart, int M)
{
  const int p = blockIdx.x*blockDim.x + threadIdx.x;
  float d = 0.0f;
  if (p < M) {
    const int u = src[p], v = dst[p];
    const float4* a = (const float4*)(psi + (size_t)u*Q);
    const float4* b = (const float4*)(psi + (size_t)v*Q);
    #pragma unroll
    for (int i=0;i<4;i++){
      float4 x=a[i], y=b[i];
      d += x.x*y.x + x.y*y.y + x.z*y.z + x.w*y.w;
    }
    d *= 2.0f;   // each pair appears twice in the directed edge list
  }
  float s = wsum(d);
  __shared__ float sm[4];
  if ((threadIdx.x & 63) == 0) sm[threadIdx.x>>6] = s;
  __syncthreads();
  if (threadIdx.x == 0) edgepart[blockIdx.x] = sm[0]+sm[1]+sm[2]+sm[3];
}

__global__ void __launch_bounds__(256) k_node_stats(
    const float* __restrict__ psi, const int* __restrict__ deg,
    float* __restrict__ colpart, float* __restrict__ degpart,
    float* __restrict__ entpart, int N)
{
  const int n = blockIdx.x*blockDim.x + threadIdx.x;
  float pv[Q]; float dg = 0.0f; float ent = 0.0f;
  if (n < N) {
    const float4* a = (const float4*)(psi + (size_t)n*Q);
    #pragma unroll
    for (int i=0;i<4;i++){ float4 t=a[i]; pv[4*i]=t.x; pv[4*i+1]=t.y; pv[4*i+2]=t.z; pv[4*i+3]=t.w; }
    dg = (float)deg[n];
    #pragma unroll
    for (int q=0;q<Q;q++) ent -= pv[q]*__logf(pv[q]+1e-12f);
  } else {
    #pragma unroll
    for (int q=0;q<Q;q++) pv[q]=0.0f;
  }
  __shared__ float smc[4][Q], smd[4][Q], sme[4];
  const int wid = threadIdx.x>>6, lane = threadIdx.x&63;
  #pragma unroll
  for (int q=0;q<Q;q++){
    float s  = wsum(pv[q]);
    float s2 = wsum(pv[q]*dg);
    if (lane == 0){ smc[wid][q]=s; smd[wid][q]=s2; }
  }
  float se = wsum(ent);
  if (lane == 0) sme[wid] = se;
  __syncthreads();
  if (threadIdx.x < Q){
    colpart[(size_t)blockIdx.x*Q+threadIdx.x] =
      smc[0][threadIdx.x]+smc[1][threadIdx.x]+smc[2][threadIdx.x]+smc[3][threadIdx.x];
    degpart[(size_t)blockIdx.x*Q+threadIdx.x] =
      smd[0][threadIdx.x]+smd[1][threadIdx.x]+smd[2][threadIdx.x]+smd[3][threadIdx.x];
  }
  if (threadIdx.x == 0) entpart[blockIdx.x] = sme[0]+sme[1]+sme[2]+sme[3];
}

__global__ void __launch_bounds__(256) k_finalize(
    const float* __restrict__ edgepart, int ne,
    const float* __restrict__ colpart, const float* __restrict__ degpart,
    const float* __restrict__ entpart, int nbn,
    float* __restrict__ out, int N, float m2, int NQ)
{
  __shared__ float sm[16][Q];
  __shared__ float red[4];
  const int t = threadIdx.x, g = t>>4, q = t&15;
  float cs=0.0f, ds=0.0f;
  for (int b=g; b<nbn; b+=16){ cs += colpart[(size_t)b*Q+q]; ds += degpart[(size_t)b*Q+q]; }
  sm[g][q] = cs; __syncthreads();
  float colq = 0.0f;
  if (t < Q){ for (int i=0;i<16;i++) colq += sm[i][t]; }
  __syncthreads();
  sm[g][q] = ds; __syncthreads();
  float degq = 0.0f;
  if (t < Q){ for (int i=0;i<16;i++) degq += sm[i][t]; }
  __syncthreads();
  float es = 0.0f;
  for (int i=t; i<ne; i+=256) es += edgepart[i];
  es = wsum(es);
  if ((t&63)==0) red[t>>6] = es;
  __syncthreads();
  const float edge_total = red[0]+red[1]+red[2]+red[3];
  __syncthreads();
  float en = 0.0f;
  for (int i=t; i<nbn; i+=256) en += entpart[i];
  en = wsum(en);
  if ((t&63)==0) red[t>>6] = en;
  __syncthreads();
  const float ent_total = red[0]+red[1]+red[2]+red[3];
  __syncthreads();
  if (t < Q){ sm[0][t] = colq; sm[1][t] = degq; }
  __syncthreads();
  if (t == 0){
    float reg = 0.0f, dt = 0.0f;
    for (int i=0;i<Q;i++){
      float d = sm[0][i]/(float)N - 1.0f/(float)Q; reg += d*d;
      float s = sm[1][i]/m2; dt += s*s;
    }
    out[NQ+0] = reg * 4.0f;                                // * sqrt(16)
    out[NQ+1] = ent_total/(float)N / 2.7725887222397811f;  // / log(16)
    out[NQ+2] = edge_total/m2 - dt;
  }
}

extern "C" void kernel_launch(void* const* d_in, const int* in_sizes, int n_in,
                              void* d_out, int out_size, void* d_ws, size_t ws_size,
                              hipStream_t stream)
{
  const int*   src   = (const int*)  d_in[0];
  const int*   dst   = (const int*)  d_in[1];
  // d_in[2] = rev : structurally rev[p]=p+M / p-M, exploited directly
  const float* psi0  = (const float*)d_in[3];
  const float* msg0  = (const float*)d_in[4];
  const float* betap = (const float*)d_in[5];

  const int E  = in_sizes[0];
  const int M  = E/2;
  const int NQ = in_sizes[3];
  const int N  = NQ/Q;
  const float mean_w = (float)((double)E/((double)N*(double)N));
  const float m2 = (float)E;

  const int B = 256;
  const int gE = (E+B-1)/B, gM = (M+B-1)/B, gN = (N+B-1)/B;
  const int nb = (N+SCAN_B-1)/SCAN_B;
  const int nbE = 2048;                          // edge grid (grid-stride)
  const int nbG = 1024;                          // gather grid (grid-stride)
  const int HPROWS = (nbG > gN ? nbG : gN);

  char* w = (char*)d_ws;
  float* msgA    = (float*)w; w += (size_t)E*Q*sizeof(float);
  float* nl      = (float*)w; w += (size_t)NQ*sizeof(float);
  int*   eid     = (int*)  w; w += (size_t)E*sizeof(int);
  int*   offs    = (int*)  w; w += (size_t)(N+16)*sizeof(int);
  int*   cursor  = (int*)  w; w += (size_t)(N+16)*sizeof(int);
  int*   bsum    = (int*)  w; w += 256*sizeof(int);
  float* hpart   = (float*)w; w += (size_t)HPROWS*Q*sizeof(float);
  float* diffpart= (float*)w; w += (size_t)nbE*sizeof(float);
  float* edgepart= (float*)w; w += (size_t)gM*sizeof(float);
  float* colpart = (float*)w; w += (size_t)gN*Q*sizeof(float);
  float* degpart = (float*)w; w += (size_t)gN*Q*sizeof(float);
  float* entpart = (float*)w; w += (size_t)gN*sizeof(float);
  int*   deg     = (int*)  w; w += (size_t)(N+16)*sizeof(int);   // memset from here
  float* h       = (float*)w; w += 16*sizeof(float);
  int*   donep   = (int*)  w; w += 4*sizeof(int);
  int*   cnt     = (int*)  w; w += 16*sizeof(int);               // per-iter arrival counters

  float* psi = (float*)d_out;   // [N,Q]; scalars at NQ..NQ+2

  const size_t small_bytes = (size_t)((char*)w - (char*)deg);
  hipMemsetAsync(deg, 0, small_bytes, stream);   // deg, h, done, cnt

  // one-time: h0, CSR build, initial node_log
  k_h_part<<<gN,B,0,stream>>>(psi0, hpart, N);
  k_hfin  <<<1, B,0,stream>>>(hpart, h, betap, gN, mean_w);
  k_deg   <<<gE,B,0,stream>>>(dst, deg, E);
  k_scan1 <<<nb,SCAN_B,0,stream>>>(deg, offs, bsum, N);
  k_scan2 <<<1, SCAN_B,0,stream>>>(bsum, nb);
  k_scan3 <<<nb,SCAN_B,0,stream>>>(offs, cursor, bsum, N, E);
  k_fill  <<<gE,B,0,stream>>>(dst, cursor, eid, E);
  k_gather2<<<nbG,B,0,stream>>>(msg0, offs, eid, nl, h, psi, betap,
                                donep, hpart, diffpart, nbE, h, cnt,
                                nbG, mean_w, N, 0);

  for (int k=0; k<10; ++k) {
    const float* mc = (k==0) ? msg0 : msgA;
    k_edge16 <<<nbE,B,0,stream>>>(src, dst, mc, msgA, nl, h, betap,
                                  diffpart, donep, M);
    k_gather2<<<nbG,B,0,stream>>>(msgA, offs, eid, nl, h, psi, betap,
                                  donep, hpart, diffpart, nbE, h, &cnt[k],
                                  nbG, mean_w, N, 1);
  }

  k_edge_term <<<gM,B,0,stream>>>(src, dst, psi, edgepart, M);
  k_node_stats<<<gN,B,0,stream>>>(psi, deg, colpart, degpart, entpart, N);
  k_finalize  <<<1,B,0,stream>>>(edgepart, gM, colpart, degpart, entpart, gN,
                                 psi, N, m2, NQ);
}

// Round 10
// 1022.623 us; speedup vs baseline: 3.2717x; 1.9363x over previous
//
#include <hip/hip_runtime.h>

#define Q 16
#define SCAN_B 256

__device__ __forceinline__ float wsum(float v){
  #pragma unroll
  for(int o=32;o;o>>=1) v += __shfl_xor(v,o);
  return v;
}
__device__ __forceinline__ float wmaxr(float v){
  #pragma unroll
  for(int o=32;o;o>>=1) v = fmaxf(v,__shfl_xor(v,o));
  return v;
}

// ---- edge kernel: 16 lanes per undirected pair, one q per lane ----
// Messages live in CSR-dst order (msgC); this kernel reads/writes its two
// rows at ipos[p] / ipos[p+M] (scattered 64B, independent -> good MLP).
__global__ void __launch_bounds__(256, 4) k_edge16C(
    const int* __restrict__ src, const int* __restrict__ dst,
    const int* __restrict__ ipos,
    float* msgC, const float* __restrict__ nl, const float* __restrict__ hc,
    const float* __restrict__ betap,
    float* __restrict__ diffpart, const int* __restrict__ donep, int M)
{
  if (*donep) return;
  const float eb = __expf(*betap) - 1.0f;
  const int q = threadIdx.x & 15;
  const float hq = hc[q];
  const int grp  = (blockIdx.x*blockDim.x + threadIdx.x) >> 4;
  const int ngrp = (gridDim.x*blockDim.x) >> 4;
  float dloc = 0.0f;
  for (int p = grp; p < M; p += ngrp){
    const int u = src[p], v = dst[p];
    const int ip0 = ipos[p];                 // row of u->v in CSR order
    const int ip1 = ipos[p + M];             // row of v->u
    const float muv = msgC[(size_t)ip0*Q + q];
    const float mvu = msgC[(size_t)ip1*Q + q];
    const float nlu = nl[(size_t)u*Q + q];
    const float nlv = nl[(size_t)v*Q + q];
    const float lsuv = __logf(fmaf(muv, eb, 1.0f));   // logS of u->v
    const float lsvu = __logf(fmaf(mvu, eb, 1.0f));   // logS of v->u
    float tuv = nlu - lsvu + hq;                      // cavity removes reverse
    float tvu = nlv - lsuv + hq;
    float m1 = tuv, m2 = tvu;
    #pragma unroll
    for (int o=1;o<16;o<<=1){
      m1 = fmaxf(m1, __shfl_xor(m1,o));
      m2 = fmaxf(m2, __shfl_xor(m2,o));
    }
    const float e1 = __expf(tuv-m1), e2 = __expf(tvu-m2);
    float s1 = e1, s2 = e2;
    #pragma unroll
    for (int o=1;o<16;o<<=1){
      s1 += __shfl_xor(s1,o);
      s2 += __shfl_xor(s2,o);
    }
    const float nuv = e1/s1, nvu = e2/s2;
    float d1 = fabsf(nuv-muv), d2 = fabsf(nvu-mvu);
    #pragma unroll
    for (int o=1;o<16;o<<=1){
      d1 += __shfl_xor(d1,o);
      d2 += __shfl_xor(d2,o);
    }
    dloc = fmaxf(dloc, fmaxf(d1,d2));
    msgC[(size_t)ip0*Q + q] = nuv;           // in-place: pair owned by one group
    msgC[(size_t)ip1*Q + q] = nvu;
  }
  __shared__ float smx[4];
  float wm = wmaxr(dloc);
  if ((threadIdx.x & 63) == 0) smx[threadIdx.x>>6] = wm;
  __syncthreads();
  if (threadIdx.x == 0)
    diffpart[blockIdx.x] = fmaxf(fmaxf(smx[0],smx[1]), fmaxf(smx[2],smx[3]));
}

// ---- gather: one wave per node (12500 blocks: many short waves — R9 lesson);
// CSR-ordered msgC means each node's rows are CONTIGUOUS: streaming coalesced
// loads with data-independent addresses (no eid chain). mode=1: psi + hpart.
__global__ void __launch_bounds__(256, 4) k_gatherC(
    const float* __restrict__ msgC, const int* __restrict__ offs,
    float* __restrict__ nl, const float* __restrict__ hc,
    float* __restrict__ psi, const float* __restrict__ betap,
    const int* __restrict__ donep, float* __restrict__ hpart,
    int N, int mode)
{
  if (mode && *donep) return;
  const int wid = threadIdx.x >> 6;                 // 0..3
  const int n = blockIdx.x*4 + wid;
  const float eb = __expf(*betap) - 1.0f;
  const int lane = threadIdx.x & 63;
  const int sub = lane >> 4, q16 = lane & 15;
  int start = 0, end = 0;
  if (n < N){ start = offs[n]; end = offs[n+1]; }
  float acc = 0.0f;
  int i = start + sub;
  for (; i + 4 < end; i += 8){
    const float x0 = msgC[(size_t)i*Q + q16];
    const float x1 = msgC[(size_t)(i+4)*Q + q16];
    acc += __logf(fmaf(x0, eb, 1.0f)) + __logf(fmaf(x1, eb, 1.0f));
  }
  if (i < end) acc += __logf(fmaf(msgC[(size_t)i*Q + q16], eb, 1.0f));
  acc += __shfl_xor(acc, 16);
  acc += __shfl_xor(acc, 32);
  if (n < N && sub == 0) nl[(size_t)n*Q + q16] = acc;
  if (!mode) return;
  float t = acc + hc[q16];
  float m = t;
  #pragma unroll
  for (int o=1;o<16;o<<=1) m = fmaxf(m, __shfl_xor(m,o));
  float ex = __expf(t-m);
  float s = ex;
  #pragma unroll
  for (int o=1;o<16;o<<=1) s += __shfl_xor(s,o);
  const float pq = ex/s;
  if (n < N && sub == 0) psi[(size_t)n*Q + q16] = pq;
  __shared__ float smh[4][17];
  if (sub == 0) smh[wid][q16] = (n < N) ? pq : 0.0f;
  __syncthreads();
  if (threadIdx.x < Q)
    hpart[(size_t)blockIdx.x*Q + threadIdx.x] =
      smh[0][threadIdx.x]+smh[1][threadIdx.x]+smh[2][threadIdx.x]+smh[3][threadIdx.x];
}

// ---- merged per-iteration reduce (R7-proven): hred + last block h/done ----
__global__ void __launch_bounds__(256) k_hred2(
    const float* __restrict__ hpart, int nrows,
    float* __restrict__ hpart2, int gH,
    const float* __restrict__ diffpart, int nbd,
    float* __restrict__ h, int* __restrict__ donep,
    int* __restrict__ cnt,
    const float* __restrict__ betap, float mean_w)
{
  if (*donep) return;
  const int t = threadIdx.x, g = t>>4, q = t&15;
  __shared__ float sm[16][17];
  {
    const int base = blockIdx.x*256;
    const int lim = min(base+256, nrows);
    float s = 0.0f;
    for (int r = base+g; r < lim; r += 16) s += hpart[(size_t)r*Q + q];
    sm[g][q] = s; __syncthreads();
    if (t < Q){
      float tot = 0.0f;
      #pragma unroll
      for (int i=0;i<16;i++) tot += sm[i][t];
      hpart2[(size_t)blockIdx.x*Q + t] = tot;
    }
  }
  __shared__ int amLast;
  __threadfence();
  if (t == 0) amLast = (atomicAdd(cnt, 1) == gH-1);
  __syncthreads();
  if (!amLast) return;
  {
    float s = 0.0f;
    for (int b = g; b < gH; b += 16) s += hpart2[(size_t)b*Q + q];
    __syncthreads();
    sm[g][q] = s; __syncthreads();
    if (t < Q){
      float tot = 0.0f;
      #pragma unroll
      for (int i=0;i<16;i++) tot += sm[i][t];
      h[t] = -(*betap) * mean_w * tot;
    }
  }
  float m = 0.0f;
  for (int i = t; i < nbd; i += 256) m = fmaxf(m, diffpart[i]);
  m = wmaxr(m);
  __shared__ float red[4];
  if ((t & 63) == 0) red[t>>6] = m;
  __syncthreads();
  if (t == 0 &&
      fmaxf(fmaxf(red[0],red[1]), fmaxf(red[2],red[3])) < 0.01f) *donep = 1;
}

// ---- h partials over psi0 (init only) ----
__global__ void __launch_bounds__(256) k_h_part(
    const float* __restrict__ psi, float* __restrict__ hpart, int N)
{
  const int n = blockIdx.x*blockDim.x + threadIdx.x;
  float pv[Q];
  if (n < N) {
    const float4* a = (const float4*)(psi + (size_t)n*Q);
    #pragma unroll
    for (int i=0;i<4;i++){ float4 t=a[i]; pv[4*i]=t.x; pv[4*i+1]=t.y; pv[4*i+2]=t.z; pv[4*i+3]=t.w; }
  } else {
    #pragma unroll
    for (int q=0;q<Q;q++) pv[q]=0.0f;
  }
  __shared__ float sm[4][Q];
  const int wid = threadIdx.x>>6, lane = threadIdx.x&63;
  #pragma unroll
  for (int q=0;q<Q;q++){
    float s = wsum(pv[q]);
    if (lane == 0) sm[wid][q] = s;
  }
  __syncthreads();
  if (threadIdx.x < Q)
    hpart[(size_t)blockIdx.x*Q + threadIdx.x] =
      sm[0][threadIdx.x]+sm[1][threadIdx.x]+sm[2][threadIdx.x]+sm[3][threadIdx.x];
}

__global__ void __launch_bounds__(256) k_hfin(
    const float* __restrict__ hpart, float* __restrict__ h,
    const float* __restrict__ betap, int nb, float mean_w)
{
  const int t = threadIdx.x, g = t>>4, q = t&15;
  float s = 0.0f;
  for (int b = g; b < nb; b += 16) s += hpart[(size_t)b*Q + q];
  __shared__ float sm[16][17];
  sm[g][q] = s; __syncthreads();
  if (t < Q){
    float tot = 0.0f;
    #pragma unroll
    for (int i=0;i<16;i++) tot += sm[i][t];
    h[t] = -(*betap) * mean_w * tot;
  }
}

// ---- CSR build ----
__global__ void __launch_bounds__(256) k_deg(
    const int* __restrict__ dst, int* __restrict__ deg, int E)
{
  const int e = blockIdx.x*blockDim.x + threadIdx.x;
  if (e < E) atomicAdd(&deg[dst[e]], 1);
}

__global__ void __launch_bounds__(SCAN_B) k_scan1(
    const int* __restrict__ deg, int* __restrict__ offs,
    int* __restrict__ bsum, int N)
{
  __shared__ int sm[SCAN_B];
  const int i = blockIdx.x*SCAN_B + threadIdx.x;
  const int v = (i<N) ? deg[i] : 0;
  sm[threadIdx.x] = v; __syncthreads();
  #pragma unroll
  for (int o=1;o<SCAN_B;o<<=1){
    int t = (threadIdx.x>=o) ? sm[threadIdx.x-o] : 0;
    __syncthreads();
    sm[threadIdx.x] += t;
    __syncthreads();
  }
  if (i<N) offs[i] = sm[threadIdx.x] - v;           // block-local exclusive
  if (threadIdx.x==SCAN_B-1) bsum[blockIdx.x] = sm[threadIdx.x];
}

__global__ void __launch_bounds__(SCAN_B) k_scan2(int* __restrict__ bsum, int nb)
{
  __shared__ int sm[SCAN_B];
  const int v = (threadIdx.x<nb) ? bsum[threadIdx.x] : 0;
  sm[threadIdx.x] = v; __syncthreads();
  #pragma unroll
  for (int o=1;o<SCAN_B;o<<=1){
    int t = (threadIdx.x>=o) ? sm[threadIdx.x-o] : 0;
    __syncthreads();
    sm[threadIdx.x] += t;
    __syncthreads();
  }
  if (threadIdx.x<nb) bsum[threadIdx.x] = sm[threadIdx.x] - v;  // exclusive
}

__global__ void __launch_bounds__(SCAN_B) k_scan3(
    int* __restrict__ offs, int* __restrict__ cursor,
    const int* __restrict__ bsum, int N, int E)
{
  const int i = blockIdx.x*SCAN_B + threadIdx.x;
  if (i<N){
    const int o = offs[i] + bsum[blockIdx.x];
    offs[i] = o; cursor[i] = o;
  }
  if (i==0) offs[N] = E;
}

// ---- fill: ipos[e] = CSR slot of edge e (coalesced write, no eid scatter) ----
__global__ void __launch_bounds__(256) k_fillC(
    const int* __restrict__ dst, int* __restrict__ cursor,
    int* __restrict__ ipos, int E)
{
  const int e = blockIdx.x*blockDim.x + threadIdx.x;
  if (e < E) ipos[e] = atomicAdd(&cursor[dst[e]], 1);
}

// ---- one-time scatter msg0 -> msgC (CSR order) ----
__global__ void __launch_bounds__(256) k_scatter0(
    const float* __restrict__ msg0, const int* __restrict__ ipos,
    float* __restrict__ msgC, int E)
{
  const int e = blockIdx.x*blockDim.x + threadIdx.x;
  if (e >= E) return;
  const int ip = ipos[e];
  const float4* s = (const float4*)(msg0 + (size_t)e*Q);
  float4* d = (float4*)(msgC + (size_t)ip*Q);
  float4 x0=s[0], x1=s[1], x2=s[2], x3=s[3];
  d[0]=x0; d[1]=x1; d[2]=x2; d[3]=x3;
}

// ---- finalization: per-block partials, no atomics ----
__global__ void __launch_bounds__(256) k_edge_term(
    const int* __restrict__ src, const int* __restrict__ dst,
    const float* __restrict__ psi, float* __restrict__ edgepart, int M)
{
  const int p = blockIdx.x*blockDim.x + threadIdx.x;
  float d = 0.0f;
  if (p < M) {
    const int u = src[p], v = dst[p];
    const float4* a = (const float4*)(psi + (size_t)u*Q);
    const float4* b = (const float4*)(psi + (size_t)v*Q);
    #pragma unroll
    for (int i=0;i<4;i++){
      float4 x=a[i], y=b[i];
      d += x.x*y.x + x.y*y.y + x.z*y.z + x.w*y.w;
    }
    d *= 2.0f;   // each pair appears twice in the directed edge list
  }
  float s = wsum(d);
  __shared__ float sm[4];
  if ((threadIdx.x & 63) == 0) sm[threadIdx.x>>6] = s;
  __syncthreads();
  if (threadIdx.x == 0) edgepart[blockIdx.x] = sm[0]+sm[1]+sm[2]+sm[3];
}

__global__ void __launch_bounds__(256) k_node_stats(
    const float* __restrict__ psi, const int* __restrict__ deg,
    float* __restrict__ colpart, float* __restrict__ degpart,
    float* __restrict__ entpart, int N)
{
  const int n = blockIdx.x*blockDim.x + threadIdx.x;
  float pv[Q]; float dg = 0.0f; float ent = 0.0f;
  if (n < N) {
    const float4* a = (const float4*)(psi + (size_t)n*Q);
    #pragma unroll
    for (int i=0;i<4;i++){ float4 t=a[i]; pv[4*i]=t.x; pv[4*i+1]=t.y; pv[4*i+2]=t.z; pv[4*i+3]=t.w; }
    dg = (float)deg[n];
    #pragma unroll
    for (int q=0;q<Q;q++) ent -= pv[q]*__logf(pv[q]+1e-12f);
  } else {
    #pragma unroll
    for (int q=0;q<Q;q++) pv[q]=0.0f;
  }
  __shared__ float smc[4][Q], smd[4][Q], sme[4];
  const int wid = threadIdx.x>>6, lane = threadIdx.x&63;
  #pragma unroll
  for (int q=0;q<Q;q++){
    float s  = wsum(pv[q]);
    float s2 = wsum(pv[q]*dg);
    if (lane == 0){ smc[wid][q]=s; smd[wid][q]=s2; }
  }
  float se = wsum(ent);
  if (lane == 0) sme[wid] = se;
  __syncthreads();
  if (threadIdx.x < Q){
    colpart[(size_t)blockIdx.x*Q+threadIdx.x] =
      smc[0][threadIdx.x]+smc[1][threadIdx.x]+smc[2][threadIdx.x]+smc[3][threadIdx.x];
    degpart[(size_t)blockIdx.x*Q+threadIdx.x] =
      smd[0][threadIdx.x]+smd[1][threadIdx.x]+smd[2][threadIdx.x]+smd[3][threadIdx.x];
  }
  if (threadIdx.x == 0) entpart[blockIdx.x] = sme[0]+sme[1]+sme[2]+sme[3];
}

__global__ void __launch_bounds__(256) k_finalize(
    const float* __restrict__ edgepart, int ne,
    const float* __restrict__ colpart, const float* __restrict__ degpart,
    const float* __restrict__ entpart, int nbn,
    float* __restrict__ out, int N, float m2, int NQ)
{
  __shared__ float sm[16][Q];
  __shared__ float red[4];
  const int t = threadIdx.x, g = t>>4, q = t&15;
  float cs=0.0f, ds=0.0f;
  for (int b=g; b<nbn; b+=16){ cs += colpart[(size_t)b*Q+q]; ds += degpart[(size_t)b*Q+q]; }
  sm[g][q] = cs; __syncthreads();
  float colq = 0.0f;
  if (t < Q){ for (int i=0;i<16;i++) colq += sm[i][t]; }
  __syncthreads();
  sm[g][q] = ds; __syncthreads();
  float degq = 0.0f;
  if (t < Q){ for (int i=0;i<16;i++) degq += sm[i][t]; }
  __syncthreads();
  float es = 0.0f;
  for (int i=t; i<ne; i+=256) es += edgepart[i];
  es = wsum(es);
  if ((t&63)==0) red[t>>6] = es;
  __syncthreads();
  const float edge_total = red[0]+red[1]+red[2]+red[3];
  __syncthreads();
  float en = 0.0f;
  for (int i=t; i<nbn; i+=256) en += entpart[i];
  en = wsum(en);
  if ((t&63)==0) red[t>>6] = en;
  __syncthreads();
  const float ent_total = red[0]+red[1]+red[2]+red[3];
  __syncthreads();
  if (t < Q){ sm[0][t] = colq; sm[1][t] = degq; }
  __syncthreads();
  if (t == 0){
    float reg = 0.0f, dt = 0.0f;
    for (int i=0;i<Q;i++){
      float d = sm[0][i]/(float)N - 1.0f/(float)Q; reg += d*d;
      float s = sm[1][i]/m2; dt += s*s;
    }
    out[NQ+0] = reg * 4.0f;                                // * sqrt(16)
    out[NQ+1] = ent_total/(float)N / 2.7725887222397811f;  // / log(16)
    out[NQ+2] = edge_total/m2 - dt;
  }
}

extern "C" void kernel_launch(void* const* d_in, const int* in_sizes, int n_in,
                              void* d_out, int out_size, void* d_ws, size_t ws_size,
                              hipStream_t stream)
{
  const int*   src   = (const int*)  d_in[0];
  const int*   dst   = (const int*)  d_in[1];
  // d_in[2] = rev : structurally rev[p]=p+M / p-M, exploited directly
  const float* psi0  = (const float*)d_in[3];
  const float* msg0  = (const float*)d_in[4];
  const float* betap = (const float*)d_in[5];

  const int E  = in_sizes[0];
  const int M  = E/2;
  const int NQ = in_sizes[3];
  const int N  = NQ/Q;
  const float mean_w = (float)((double)E/((double)N*(double)N));
  const float m2 = (float)E;

  const int B = 256;
  const int gE = (E+B-1)/B, gM = (M+B-1)/B, gN = (N+B-1)/B;
  const int nb = (N+SCAN_B-1)/SCAN_B;
  const int nbE = 2048;                          // edge grid (grid-stride)
  const int gW = (N+3)/4;                        // gather: one wave per node
  const int gH = (gW+255)/256;                   // hred blocks (~49)
  const int HPROWS = (gW > gN ? gW : gN);

  char* w = (char*)d_ws;
  float* msgC    = (float*)w; w += (size_t)E*Q*sizeof(float);
  float* nl      = (float*)w; w += (size_t)NQ*sizeof(float);
  int*   ipos    = (int*)  w; w += (size_t)E*sizeof(int);
  int*   offs    = (int*)  w; w += (size_t)(N+16)*sizeof(int);
  int*   cursor  = (int*)  w; w += (size_t)(N+16)*sizeof(int);
  int*   bsum    = (int*)  w; w += 256*sizeof(int);
  float* hpart   = (float*)w; w += (size_t)HPROWS*Q*sizeof(float);
  float* hpart2  = (float*)w; w += (size_t)gH*Q*sizeof(float);
  float* diffpart= (float*)w; w += (size_t)nbE*sizeof(float);
  float* edgepart= (float*)w; w += (size_t)gM*sizeof(float);
  float* colpart = (float*)w; w += (size_t)gN*Q*sizeof(float);
  float* degpart = (float*)w; w += (size_t)gN*Q*sizeof(float);
  float* entpart = (float*)w; w += (size_t)gN*sizeof(float);
  int*   deg     = (int*)  w; w += (size_t)(N+16)*sizeof(int);   // memset from here
  float* h       = (float*)w; w += 16*sizeof(float);
  int*   donep   = (int*)  w; w += 4*sizeof(int);
  int*   cnt     = (int*)  w; w += 16*sizeof(int);               // per-iter arrival counters

  float* psi = (float*)d_out;   // [N,Q]; scalars at NQ..NQ+2

  const size_t small_bytes = (size_t)((char*)w - (char*)deg);
  hipMemsetAsync(deg, 0, small_bytes, stream);   // deg, h, done, cnt

  // one-time: h0, CSR build (ipos), scatter msg0->msgC, initial node_log
  k_h_part  <<<gN,B,0,stream>>>(psi0, hpart, N);
  k_hfin    <<<1, B,0,stream>>>(hpart, h, betap, gN, mean_w);
  k_deg     <<<gE,B,0,stream>>>(dst, deg, E);
  k_scan1   <<<nb,SCAN_B,0,stream>>>(deg, offs, bsum, N);
  k_scan2   <<<1, SCAN_B,0,stream>>>(bsum, nb);
  k_scan3   <<<nb,SCAN_B,0,stream>>>(offs, cursor, bsum, N, E);
  k_fillC   <<<gE,B,0,stream>>>(dst, cursor, ipos, E);
  k_scatter0<<<gE,B,0,stream>>>(msg0, ipos, msgC, E);
  k_gatherC <<<gW,B,0,stream>>>(msgC, offs, nl, h, psi, betap, donep, hpart, N, 0);

  for (int k=0; k<10; ++k) {
    k_edge16C<<<nbE,B,0,stream>>>(src, dst, ipos, msgC, nl, h, betap,
                                  diffpart, donep, M);
    k_gatherC<<<gW,B,0,stream>>>(msgC, offs, nl, h, psi, betap, donep,
                                 hpart, N, 1);
    k_hred2  <<<gH,B,0,stream>>>(hpart, gW, hpart2, gH, diffpart, nbE,
                                 h, donep, &cnt[k], betap, mean_w);
  }

  k_edge_term <<<gM,B,0,stream>>>(src, dst, psi, edgepart, M);
  k_node_stats<<<gN,B,0,stream>>>(psi, deg, colpart, degpart, entpart, N);
  k_finalize  <<<1,B,0,stream>>>(edgepart, gM, colpart, degpart, entpart, gN,
                                 psi, N, m2, NQ);
}